// Round 7
// baseline (733.541 us; speedup 1.0000x reference)
//
#include <hip/hip_runtime.h>

#define N_ROWS 131072
#define DIM 64
#define K_CODES 4096
#define NCH (K_CODES / 64)     // 64 chunks of 64 codes
#define P_PARTS 4              // privatized scatter copies
#define EPS 0.00390625f        // 1/256: >=13x typical bf16x3 error bound

typedef __attribute__((ext_vector_type(8))) short short8;
typedef __attribute__((ext_vector_type(4))) float f32x4;

__device__ inline unsigned short bf16rn(float f) {   // round-nearest-even
    unsigned int u = __float_as_uint(f);
    u += 0x7FFFu + ((u >> 16) & 1u);
    return (unsigned short)(u >> 16);
}
__device__ inline float bfhi(unsigned short h) {
    return __uint_as_float(((unsigned int)h) << 16);
}
__device__ inline unsigned int fkey(float f) {       // order-preserving (finite)
    unsigned int u = __float_as_uint(f);
    return (u & 0x80000000u) ? ~u : (u | 0x80000000u);
}

// ---- prep: embed -> bf16 hi/lo in MFMA B-frag layout, + exact e2 ----
// frag addr (short8 units) for (code c, k-group s,q): chunk*512 + j*128 + s*64 + q*16 + (c&15)
// where chunk=c>>6, j=(c>>4)&3. Dist reads lane L=q*16+l15 at [(j*2+s)*64 + L].
__global__ void prep_kernel(const float* __restrict__ embed,
                            uint4* __restrict__ fh, uint4* __restrict__ fl,
                            float* __restrict__ e2) {
    const int c = blockIdx.x * blockDim.x + threadIdx.x;  // one thread per code
    float w[DIM];
    const float4* ep = (const float4*)(embed + (size_t)c * DIM);
    float s = 0.f;
#pragma unroll
    for (int i = 0; i < 16; ++i) {
        float4 v = ep[i];
        w[4 * i] = v.x; w[4 * i + 1] = v.y; w[4 * i + 2] = v.z; w[4 * i + 3] = v.w;
        s = fmaf(v.x, v.x, s); s = fmaf(v.y, v.y, s);
        s = fmaf(v.z, v.z, s); s = fmaf(v.w, v.w, s);
    }
    e2[c] = s;
    const size_t base = (size_t)(c >> 6) * 512 + ((c >> 4) & 3) * 128 + (c & 15);
#pragma unroll
    for (int sd = 0; sd < 2; ++sd)
#pragma unroll
        for (int q = 0; q < 4; ++q) {
            unsigned short hb[8], lb[8];
#pragma unroll
            for (int m = 0; m < 8; ++m) {
                float v = w[32 * sd + 8 * q + m];
                hb[m] = bf16rn(v);
                lb[m] = bf16rn(v - bfhi(hb[m]));
            }
            const size_t off = base + sd * 64 + q * 16;
            fh[off] = *(uint4*)hb;
            fl[off] = *(uint4*)lb;
        }
}

// ---- MFMA distance + fused top-2 argmin: no LDS, no barriers ----
// Wave owns 64 rows; A = bf16 split of (-2x) in regs; C init = e2 => score = acc.
__global__ __launch_bounds__(256, 2) void dist_argmin_kernel(
        const float* __restrict__ x,
        const short8* __restrict__ fh, const short8* __restrict__ fl,
        const float* __restrict__ e2g,
        int* __restrict__ ind_ws, float* __restrict__ ind_out,
        int* __restrict__ cnt, int* __restrict__ list,
        unsigned long long* __restrict__ pk) {
    const int tid = threadIdx.x;
    const int lane = tid & 63;
    const int l15 = tid & 15;
    const int quad = (tid >> 4) & 3;
    const int r0w = blockIdx.x * 256 + (tid >> 6) * 64;

    // A-frags: exact -2x split (scaling by -2 is exact in bf16 round)
    short8 ah[4][2], al[4][2];
#pragma unroll
    for (int i = 0; i < 4; ++i)
#pragma unroll
        for (int s = 0; s < 2; ++s) {
            const float* xp = x + (size_t)(r0w + 16 * i + l15) * DIM + 32 * s + 8 * quad;
            float4 f0 = *(const float4*)xp;
            float4 f1 = *(const float4*)(xp + 4);
            float w[8] = {f0.x, f0.y, f0.z, f0.w, f1.x, f1.y, f1.z, f1.w};
            short8 h, l;
#pragma unroll
            for (int m = 0; m < 8; ++m) {
                float v = -2.f * w[m];
                unsigned short hb = bf16rn(v);
                h[m] = (short)hb;
                l[m] = (short)bf16rn(v - bfhi(hb));
            }
            ah[i][s] = h; al[i][s] = l;
        }

    float s1[16], s2[16];
    int c1[16];
#pragma unroll
    for (int t = 0; t < 16; ++t) { s1[t] = 3.4e38f; s2[t] = 3.4e38f; c1[t] = 0; }

    const short8* ph = fh + lane;   // chunk stride = 512 short8
    const short8* pl = fl + lane;
    for (int ch = 0; ch < NCH; ++ch) {
#pragma unroll
        for (int j = 0; j < 4; ++j) {
            short8 bh0 = ph[(j * 2 + 0) * 64];
            short8 bh1 = ph[(j * 2 + 1) * 64];
            short8 bl0 = pl[(j * 2 + 0) * 64];
            short8 bl1 = pl[(j * 2 + 1) * 64];
            const float e2v = e2g[ch * 64 + 16 * j + l15];
            const f32x4 cinit = {e2v, e2v, e2v, e2v};
            const int cc = ch * 64 + 16 * j + l15;
#pragma unroll
            for (int i = 0; i < 4; ++i) {
                f32x4 a;
                a = __builtin_amdgcn_mfma_f32_16x16x32_bf16(ah[i][0], bh0, cinit, 0, 0, 0);
                a = __builtin_amdgcn_mfma_f32_16x16x32_bf16(ah[i][1], bh1, a, 0, 0, 0);
                a = __builtin_amdgcn_mfma_f32_16x16x32_bf16(ah[i][0], bl0, a, 0, 0, 0);
                a = __builtin_amdgcn_mfma_f32_16x16x32_bf16(ah[i][1], bl1, a, 0, 0, 0);
                a = __builtin_amdgcn_mfma_f32_16x16x32_bf16(al[i][0], bh0, a, 0, 0, 0);
                a = __builtin_amdgcn_mfma_f32_16x16x32_bf16(al[i][1], bh1, a, 0, 0, 0);
#pragma unroll
                for (int r = 0; r < 4; ++r) {
                    const float sc = a[r];            // = e2 - 2*dot directly
                    const int st = i * 4 + r;
                    const bool lt = sc < s1[st];
                    s2[st] = fminf(fmaxf(sc, s1[st]), s2[st]);   // med3 runner-up
                    c1[st] = lt ? cc : c1[st];
                    s1[st] = lt ? sc : s1[st];
                }
            }
        }
        ph += 512; pl += 512;
    }

    // butterfly top-2 merge across the 16 lanes sharing each row
#pragma unroll
    for (int st = 0; st < 16; ++st) {
#pragma unroll
        for (int m = 1; m < 16; m <<= 1) {
            float os1 = __shfl_xor(s1[st], m, 64);
            float os2 = __shfl_xor(s2[st], m, 64);
            int   oc1 = __shfl_xor(c1[st], m, 64);
            bool take = (os1 < s1[st]) || (os1 == s1[st] && oc1 < c1[st]);
            float loser = take ? s1[st] : os1;
            s2[st] = fminf(fminf(s2[st], os2), loser);
            if (take) { s1[st] = os1; c1[st] = oc1; }
        }
    }
    if (l15 == 0) {
#pragma unroll
        for (int st = 0; st < 16; ++st) {
            const int row = r0w + 16 * (st >> 2) + 4 * quad + (st & 3);
            ind_ws[row] = c1[st];
            ind_out[row] = (float)c1[st];
            if (s2[st] - s1[st] < EPS) {   // ambiguous under bf16x3 error
                int p = atomicAdd(cnt, 1);
                list[p] = row;
                pk[row] = ~0ull;
            }
        }
    }
}

// ---- refine: exact fp32 re-solve, batched (block = 64 rows x 1024-code slice) ----
__global__ void refine_kernel(const float* __restrict__ x,
                              const float* __restrict__ embed,
                              const float* __restrict__ e2g,
                              const int* __restrict__ cnt,
                              const int* __restrict__ list,
                              unsigned long long* __restrict__ pk) {
    const int n = *cnt;
    if (n == 0) return;
    const int lane = threadIdx.x & 63;
    const int wv = threadIdx.x >> 6;
    for (int base = blockIdx.x * 64; base < n; base += gridDim.x * 64) {
        const int idx = base + lane;
        const int srow = list[idx < n ? idx : n - 1];   // dup last: harmless re-min
        float xr[DIM];
        const float4* xp = (const float4*)(x + (size_t)srow * DIM);
#pragma unroll
        for (int q = 0; q < 16; ++q) {
            float4 v = xp[q];
            xr[4 * q] = v.x; xr[4 * q + 1] = v.y;
            xr[4 * q + 2] = v.z; xr[4 * q + 3] = v.w;
        }
        const int c0 = blockIdx.y * 1024 + wv * 256;
        unsigned long long best = ~0ull;
        for (int c = c0; c < c0 + 256; ++c) {
            const float4* ep = (const float4*)(embed + (size_t)c * DIM);
            float d0 = 0.f, d1 = 0.f, d2 = 0.f, d3 = 0.f;
#pragma unroll
            for (int q = 0; q < 16; ++q) {
                float4 ev = ep[q];
                d0 = fmaf(xr[4 * q], ev.x, d0);
                d1 = fmaf(xr[4 * q + 1], ev.y, d1);
                d2 = fmaf(xr[4 * q + 2], ev.z, d2);
                d3 = fmaf(xr[4 * q + 3], ev.w, d3);
            }
            float sc = fmaf(-2.f, (d0 + d1) + (d2 + d3), e2g[c]);
            unsigned long long key =
                ((unsigned long long)fkey(sc) << 32) | (unsigned int)c;
            if (key < best) best = key;
        }
        atomicMin(&pk[srow], best);
    }
}

// ---- unpack refined rows into ind ----
__global__ void unpack_kernel(const int* __restrict__ cnt,
                              const int* __restrict__ list,
                              const unsigned long long* __restrict__ pk,
                              int* __restrict__ ind_ws,
                              float* __restrict__ ind_out) {
    const int i = blockIdx.x * blockDim.x + threadIdx.x;
    if (i >= *cnt) return;
    const int row = list[i];
    const int k = (int)(pk[row] & 0xFFFFFFFFull);
    ind_ws[row] = k;
    ind_out[row] = (float)k;
}

// ---- scatter: float4 gather/add, P-way privatized stats ----
__global__ void scatter_kernel(const float* __restrict__ x,
                               const float* __restrict__ embed,
                               const int* __restrict__ ind,
                               float* __restrict__ quant,
                               float* __restrict__ cs_p,
                               float* __restrict__ esum_p) {
    const int t = blockIdx.x * blockDim.x + threadIdx.x;  // over N*16
    const int row = t >> 4;
    const int dq = (t & 15) * 4;
    const int k = ind[row];
    const int part = blockIdx.x & (P_PARTS - 1);
    float4 xv = *(const float4*)(x + (size_t)row * DIM + dq);
    *(float4*)(quant + (size_t)row * DIM + dq) =
        *(const float4*)(embed + (size_t)k * DIM + dq);
    float* ep = esum_p + ((size_t)part * K_CODES + k) * DIM + dq;
    atomicAdd(ep + 0, xv.x); atomicAdd(ep + 1, xv.y);
    atomicAdd(ep + 2, xv.z); atomicAdd(ep + 3, xv.w);
    if ((t & 15) == 0) atomicAdd(cs_p + part * K_CODES + k, 1.0f);
}

// ---- reduce privatized stats into d_out ----
__global__ void reduce_kernel(const float* __restrict__ esum_p,
                              const float* __restrict__ cs_p,
                              float* __restrict__ esum, float* __restrict__ cs) {
    const int i = blockIdx.x * blockDim.x + threadIdx.x;  // K*DIM
    float s = 0.f;
#pragma unroll
    for (int p = 0; p < P_PARTS; ++p) s += esum_p[(size_t)p * K_CODES * DIM + i];
    esum[i] = s;
    if (i < K_CODES) {
        float c = 0.f;
#pragma unroll
        for (int p = 0; p < P_PARTS; ++p) c += cs_p[p * K_CODES + i];
        cs[i] = c;
    }
}

extern "C" void kernel_launch(void* const* d_in, const int* in_sizes, int n_in,
                              void* d_out, int out_size, void* d_ws, size_t ws_size,
                              hipStream_t stream) {
    const float* x     = (const float*)d_in[0];
    const float* embed = (const float*)d_in[1];

    float* out     = (float*)d_out;
    float* quant   = out;                            // [N, D]
    float* ind_out = out + (size_t)N_ROWS * DIM;     // [N] (as float)
    float* cs      = ind_out + N_ROWS;               // [K]
    float* esum    = cs + K_CODES;                   // [K, D]

    // ws layout (all 16B-aligned): pk | fh | fl | e2 | list | ind_ws | cnt | esum_p | cs_p
    char* w = (char*)d_ws;
    unsigned long long* pk = (unsigned long long*)w;          w += (size_t)N_ROWS * 8;
    short8* fh   = (short8*)w;                                w += (size_t)K_CODES * DIM * 2;
    short8* fl   = (short8*)w;                                w += (size_t)K_CODES * DIM * 2;
    float*  e2   = (float*)w;                                 w += K_CODES * 4;
    int*    list = (int*)w;                                   w += (size_t)N_ROWS * 4;
    int*    ind_ws = (int*)w;                                 w += (size_t)N_ROWS * 4;
    int*    cnt  = (int*)w;                                   w += 16;
    float*  esum_p = (float*)w;                               w += (size_t)P_PARTS * K_CODES * DIM * 4;
    float*  cs_p = (float*)w;

    hipMemsetAsync(cnt, 0, 4, stream);
    hipMemsetAsync(esum_p, 0,
                   (size_t)P_PARTS * (K_CODES * DIM + K_CODES) * 4, stream);

    prep_kernel<<<K_CODES / 256, 256, 0, stream>>>(embed, (uint4*)fh, (uint4*)fl, e2);
    dist_argmin_kernel<<<N_ROWS / 256, 256, 0, stream>>>(
        x, fh, fl, e2, ind_ws, ind_out, cnt, list, pk);
    refine_kernel<<<dim3(64, 4), 256, 0, stream>>>(x, embed, e2, cnt, list, pk);
    unpack_kernel<<<N_ROWS / 256, 256, 0, stream>>>(cnt, list, pk, ind_ws, ind_out);
    scatter_kernel<<<(size_t)N_ROWS * 16 / 256, 256, 0, stream>>>(
        x, embed, ind_ws, quant, cs_p, esum_p);
    reduce_kernel<<<K_CODES * DIM / 256, 256, 0, stream>>>(esum_p, cs_p, esum, cs);
}